// Round 7
// baseline (388.889 us; speedup 1.0000x reference)
//
#include <hip/hip_runtime.h>
#include <cstdint>
#include <cstddef>

#define SEQ   2048
#define BBAT  2
#define EMBED 512
#define NH    8
#define HD    64
#define NPOS  34

typedef __bf16 bf16;
typedef __bf16 bf16x8 __attribute__((ext_vector_type(8)));
typedef float  f32x4  __attribute__((ext_vector_type(4)));

// scale = log2(e)/8 : energy=(qk+bias)/8, computed in exp2 domain
#define ESCALE 0.1803368801111204f

__device__ __forceinline__ f32x4 mfma16(bf16x8 a, bf16x8 b, f32x4 c){
  return __builtin_amdgcn_mfma_f32_16x16x32_bf16(a, b, c, 0, 0, 0);
}

// ---------------- projections: 128x128 tile, f32 inputs converted in staging ----------------
// B rows permuted during staging (free): W'[n'][k] = W[(n'&63)*8 + (n'>>6)][k].
// z==2 (V) stores transposed (b,h,d,s) via LDS. Register double-buffer on A and B.
__global__ __launch_bounds__(256,2) void k_gemm_proj(
    const float* __restrict__ Q, const float* __restrict__ K, const float* __restrict__ V,
    const float* __restrict__ Wq, const float* __restrict__ Wk, const float* __restrict__ Wv,
    bf16* __restrict__ Qp, bf16* __restrict__ Kp, bf16* __restrict__ Vt)
{
  __shared__ __align__(16) bf16 smem[18432];          // 36864 B: As[128][72] + Bs[128][72]
  bf16 (*As)[72] = (bf16(*)[72])smem;
  bf16 (*Bs)[72] = (bf16(*)[72])(smem + 9216);
  const int z = blockIdx.z;
  const float* A = z==0 ? Q : (z==1 ? K : V);
  const float* W = z==0 ? Wq : (z==1 ? Wk : Wv);
  const int t = threadIdx.x;
  const int w = t >> 6, lane = t & 63, l15 = lane & 15, quad = lane >> 4;
  const int wm = (w & 1) * 64, wn = (w >> 1) * 64;
  const int m0 = blockIdx.y * 128, n0 = blockIdx.x * 128;

  f32x4 acc[4][4];
  #pragma unroll
  for (int mt=0;mt<4;++mt)
    #pragma unroll
    for (int nt=0;nt<4;++nt) acc[mt][nt] = (f32x4){0.f,0.f,0.f,0.f};

  // prologue: load kt=0 tiles into regs
  float4 pa[8], pb[8];
  #pragma unroll
  for (int i=0;i<8;++i){
    int fl = t + 256*i, row = fl >> 4, c4 = (fl & 15) << 2;
    pa[i] = *(const float4*)(A + (size_t)(m0 + row)*512 + c4);
    int src = (((n0 + row) & 63) << 3) + ((n0 + row) >> 6);
    pb[i] = *(const float4*)(W + (size_t)src*512 + c4);
  }

  for (int kt = 0; kt < 512; kt += 64){
    // regs -> LDS with f32->bf16 convert
    #pragma unroll
    for (int i=0;i<8;++i){
      int fl = t + 256*i, row = fl >> 4, c4 = (fl & 15) << 2;
      union { bf16 e[4]; ushort4 u; } ca, cb;
      ca.e[0]=(bf16)pa[i].x; ca.e[1]=(bf16)pa[i].y; ca.e[2]=(bf16)pa[i].z; ca.e[3]=(bf16)pa[i].w;
      cb.e[0]=(bf16)pb[i].x; cb.e[1]=(bf16)pb[i].y; cb.e[2]=(bf16)pb[i].z; cb.e[3]=(bf16)pb[i].w;
      *(ushort4*)&As[row][c4] = ca.u;
      *(ushort4*)&Bs[row][c4] = cb.u;
    }
    __syncthreads();
    // prefetch next k-tile (VMEM hidden behind MFMA)
    if (kt < 448){
      #pragma unroll
      for (int i=0;i<8;++i){
        int fl = t + 256*i, row = fl >> 4, c4 = (fl & 15) << 2;
        pa[i] = *(const float4*)(A + (size_t)(m0 + row)*512 + kt + 64 + c4);
        int src = (((n0 + row) & 63) << 3) + ((n0 + row) >> 6);
        pb[i] = *(const float4*)(W + (size_t)src*512 + kt + 64 + c4);
      }
    }
    #pragma unroll
    for (int ks = 0; ks < 2; ++ks){
      bf16x8 am[4], bn[4];
      #pragma unroll
      for (int x=0;x<4;++x) am[x] = *(const bf16x8*)&As[wm + x*16 + l15][ks*32 + quad*8];
      #pragma unroll
      for (int y=0;y<4;++y) bn[y] = *(const bf16x8*)&Bs[wn + y*16 + l15][ks*32 + quad*8];
      #pragma unroll
      for (int mt=0;mt<4;++mt)
        #pragma unroll
        for (int nt=0;nt<4;++nt)
          acc[mt][nt] = mfma16(am[mt], bn[nt], acc[mt][nt]);
    }
    __syncthreads();
  }

  if (z != 2){
    bf16* C = z==0 ? Qp : Kp;
    #pragma unroll
    for (int mt=0;mt<4;++mt)
      #pragma unroll
      for (int r=0;r<4;++r){
        int m = m0 + wm + mt*16 + quad*4 + r;
        #pragma unroll
        for (int nt=0;nt<4;++nt)
          C[(size_t)m*512 + n0 + wn + nt*16 + l15] = (bf16)acc[mt][nt][r];
      }
  } else {
    // transpose via LDS overlay (As+Bs region): VT[n_local 128][m 128+pad]
    bf16 (*VT)[136] = (bf16(*)[136])smem;             // 34816 B <= 36864
    #pragma unroll
    for (int mt=0;mt<4;++mt)
      #pragma unroll
      for (int r=0;r<4;++r){
        int m = wm + mt*16 + quad*4 + r;
        #pragma unroll
        for (int nt=0;nt<4;++nt)
          VT[wn + nt*16 + l15][m] = (bf16)acc[mt][nt][r];
      }
    __syncthreads();
    const int nl = t >> 1, half = t & 1;
    const int gh = (n0 + nl) >> 6, d = (n0 + nl) & 63;
    const int b = m0 >> 11, s0 = (m0 & 2047) + half*64;
    bf16* dst = Vt + ((size_t)((b*NH + gh)*HD + d))*SEQ + s0;
    #pragma unroll
    for (int j = 0; j < 8; ++j)
      *(uint4*)(dst + j*8) = *(const uint4*)&VT[nl][half*64 + j*8];
  }
}

// ---------------- GEMM 64x64 tile (output proj, f32 out), register double-buffer ----------------
__global__ __launch_bounds__(256,2) void k_gemm_out(
    const bf16* __restrict__ A, const bf16* __restrict__ Bw, float* __restrict__ C)
{
  __shared__ __align__(16) bf16 As[64][72];
  __shared__ __align__(16) bf16 Bs[64][72];
  const int t = threadIdx.x;
  const int w = t >> 6, lane = t & 63, l15 = lane & 15, quad = lane >> 4;
  const int wm = (w & 1) * 32, wn = (w >> 1) * 32;
  const int m0 = blockIdx.y * 64, n0 = blockIdx.x * 64;

  f32x4 acc[2][2];
  #pragma unroll
  for (int mt=0; mt<2; ++mt)
    #pragma unroll
    for (int nt=0; nt<2; ++nt) acc[mt][nt] = (f32x4){0.f,0.f,0.f,0.f};

  uint4 pa[2], pb[2];
  #pragma unroll
  for (int i=0;i<2;++i){
    int lin = t + 256*i, r = lin >> 3, c8 = (lin & 7) << 3;
    pa[i] = *(const uint4*)(A  + (size_t)(m0 + r)*512 + c8);
    pb[i] = *(const uint4*)(Bw + (size_t)(n0 + r)*512 + c8);
  }

  for (int kt = 0; kt < 512; kt += 64){
    #pragma unroll
    for (int i = 0; i < 2; ++i){
      int lin = t + 256*i, r = lin >> 3, c8 = (lin & 7) << 3;
      *(uint4*)&As[r][c8] = pa[i];
      *(uint4*)&Bs[r][c8] = pb[i];
    }
    __syncthreads();
    if (kt < 448){
      #pragma unroll
      for (int i = 0; i < 2; ++i){
        int lin = t + 256*i, r = lin >> 3, c8 = (lin & 7) << 3;
        pa[i] = *(const uint4*)(A  + (size_t)(m0 + r)*512 + kt + 64 + c8);
        pb[i] = *(const uint4*)(Bw + (size_t)(n0 + r)*512 + kt + 64 + c8);
      }
    }
    #pragma unroll
    for (int ks = 0; ks < 2; ++ks){
      bf16x8 am[2], bn[2];
      #pragma unroll
      for (int x=0;x<2;++x) am[x] = *(const bf16x8*)&As[wm + x*16 + l15][ks*32 + quad*8];
      #pragma unroll
      for (int y=0;y<2;++y) bn[y] = *(const bf16x8*)&Bs[wn + y*16 + l15][ks*32 + quad*8];
      #pragma unroll
      for (int mt=0;mt<2;++mt)
        #pragma unroll
        for (int nt=0;nt<2;++nt)
          acc[mt][nt] = mfma16(am[mt], bn[nt], acc[mt][nt]);
    }
    __syncthreads();
  }
  #pragma unroll
  for (int mt=0;mt<2;++mt)
    #pragma unroll
    for (int r=0;r<4;++r){
      int m = m0 + wm + mt*16 + quad*4 + r;
      #pragma unroll
      for (int nt=0;nt<2;++nt)
        C[(size_t)m*512 + n0 + wn + nt*16 + l15] = acc[mt][nt][r];
    }
}

// ---------------- flash attention: LDS-gather bias, Ps-overlays-Ks, 4 WG/CU ----------------
// grid (32,8,2) x 256 thr. QK square wave sub-tiles (32q x 64k); PV 32q x 32d over k=128.
// lut bf16 [64][36]; bias gathered from LDS banks (TA-serialization was the ~100us wall).
// Also folds: Wop col-perm table build (for k_gemm_out) + lut B-frags read direct from RE.
__global__ __launch_bounds__(256,4) void k_attn(
    const bf16* __restrict__ Qp, const bf16* __restrict__ Kp,
    const bf16* __restrict__ Vt, const float* __restrict__ RE,
    const float* __restrict__ Wo, const int* __restrict__ ids,
    bf16* __restrict__ Out, bf16* __restrict__ Wop)
{
  // LDS: KP 18432 (Ks[128][72] / Ps[64][136] overlay) + Vs 17408 + lut 4608 + lsum 512 = 40960 B
  __shared__ __align__(16) bf16 KP[9216];
  __shared__ __align__(16) bf16 Vs[64][136];
  __shared__ bf16 lut[64][36];
  __shared__ float lsum_s[128];
  bf16 (*Ks)[72]  = (bf16(*)[72])KP;
  bf16 (*Ps)[136] = (bf16(*)[136])KP;

  const int t = threadIdx.x;
  const int b = blockIdx.z, h = blockIdx.y;
  const int q0 = blockIdx.x * 64;
  const int w = t >> 6, lane = t & 63, l15 = lane & 15, quad = lane >> 4;
  const int qh = w & 1, kh = w >> 1;

  // ---- fold: build one row of Wop (col-permuted Wo, bf16) for k_gemm_out ----
  {
    int n = blockIdx.x + 32*blockIdx.y + 256*blockIdx.z;   // [0,512)
    int kp0 = t*2, kp1 = t*2 + 1;
    int s0i = ((kp0 & 63) << 3) + (kp0 >> 6);
    int s1i = ((kp1 & 63) << 3) + (kp1 >> 6);
    Wop[(size_t)n*512 + kp0] = (bf16)Wo[(size_t)n*512 + s0i];
    Wop[(size_t)n*512 + kp1] = (bf16)Wo[(size_t)n*512 + s1i];
  }

  const size_t idb = (size_t)b*SEQ*SEQ;

  // ---- prefetch tile-0 ids (latency hidden under LUT build) ----
  int nid[2][4][4];
  #pragma unroll
  for (int mt=0; mt<2; ++mt)
    #pragma unroll
    for (int nt=0; nt<4; ++nt)
      #pragma unroll
      for (int r=0; r<4; ++r)
        nid[mt][nt][r] = ids[idb + (size_t)(q0 + qh*32 + mt*16 + quad*4 + r)*SEQ
                             + kh*64 + nt*16 + l15];

  // ---- build LUT via MFMA, B-frags direct from RE (strided f32, L2/L1-resident) ----
  {
    const bf16* qbrow = Qp + (size_t)(b*SEQ + q0 + w*16 + l15)*EMBED + h*HD;
    bf16x8 ab0 = *(const bf16x8*)(qbrow + quad*8);
    bf16x8 ab1 = *(const bf16x8*)(qbrow + 32 + quad*8);
    #pragma unroll
    for (int nt = 0; nt < 3; ++nt){
      int p = nt*16 + l15;
      bf16x8 r0, r1;
      if (p < NPOS){
        #pragma unroll
        for (int j = 0; j < 8; ++j){
          r0[j] = (bf16)RE[(size_t)p*512 + (quad*8 + j)*8 + h];
          r1[j] = (bf16)RE[(size_t)p*512 + (32 + quad*8 + j)*8 + h];
        }
      } else {
        #pragma unroll
        for (int j = 0; j < 8; ++j){ r0[j] = (bf16)0.f; r1[j] = (bf16)0.f; }
      }
      f32x4 c = (f32x4){0.f,0.f,0.f,0.f};
      c = mfma16(ab0, r0, c);
      c = mfma16(ab1, r1, c);
      if (p < NPOS){
        #pragma unroll
        for (int r = 0; r < 4; ++r)
          lut[w*16 + quad*4 + r][p] = (p == 0) ? (bf16)0.f : (bf16)exp2f(c[r]*ESCALE);
      }
    }
  }

  // ---- QK A-frags (reg-resident), rows qh*32+mt*16+l15 ----
  bf16x8 aq[2][2];
  #pragma unroll
  for (int mt = 0; mt < 2; ++mt){
    const bf16* qrow = Qp + (size_t)(b*SEQ + q0 + qh*32 + mt*16 + l15)*EMBED + h*HD;
    aq[mt][0] = *(const bf16x8*)(qrow + quad*8);
    aq[mt][1] = *(const bf16x8*)(qrow + 32 + quad*8);
  }

  const bf16* kbase = Kp + (size_t)b*SEQ*EMBED + h*HD;
  const bf16* vbase = Vt + (size_t)(b*NH + h)*HD*SEQ;

  f32x4 acc[2][2];
  #pragma unroll
  for (int mt=0;mt<2;++mt)
    #pragma unroll
    for (int nt=0;nt<2;++nt) acc[mt][nt] = (f32x4){0.f,0.f,0.f,0.f};
  float lsum[2][4] = {{0.f,0.f,0.f,0.f},{0.f,0.f,0.f,0.f}};

  for (int kt = 0; kt < 16; ++kt){
    const int k0 = kt * 128;
    // ---- stage K (128x64) and V^T (64x128) ----
    #pragma unroll
    for (int i = 0; i < 4; ++i){
      int lin = t + 256*i;
      int r = lin >> 3, c8 = (lin & 7) << 3;
      *(uint4*)&Ks[r][c8] = *(const uint4*)(kbase + (size_t)(k0 + r)*EMBED + c8);
    }
    #pragma unroll
    for (int i = 0; i < 4; ++i){
      int lin = t + 256*i;
      int d = lin >> 4, c8 = (lin & 15) << 3;
      *(uint4*)&Vs[d][c8] = *(const uint4*)(vbase + (size_t)d*SEQ + k0 + c8);
    }
    __syncthreads();                 // B1: staging done (tile 0: also LUT/Wop done)

    // ---- bias gathers from LDS LUT (indices already resident) ----
    float wv[2][4][4];
    #pragma unroll
    for (int mt = 0; mt < 2; ++mt)
      #pragma unroll
      for (int nt = 0; nt < 4; ++nt)
        #pragma unroll
        for (int r = 0; r < 4; ++r)
          wv[mt][nt][r] = (float)lut[qh*32 + mt*16 + quad*4 + r][nid[mt][nt][r]];

    // ---- prefetch next tile ids (VMEM flies under MFMA) ----
    if (kt < 15){
      #pragma unroll
      for (int mt = 0; mt < 2; ++mt)
        #pragma unroll
        for (int nt = 0; nt < 4; ++nt)
          #pragma unroll
          for (int r = 0; r < 4; ++r)
            nid[mt][nt][r] = ids[idb + (size_t)(q0 + qh*32 + mt*16 + quad*4 + r)*SEQ
                                 + (k0 + 128) + kh*64 + nt*16 + l15];
    }

    // ---- QK: wave computes 32q x 64k ----
    f32x4 sf[2][4];
    #pragma unroll
    for (int nt = 0; nt < 4; ++nt){
      bf16x8 bk0 = *(const bf16x8*)&Ks[kh*64 + nt*16 + l15][quad*8];
      bf16x8 bk1 = *(const bf16x8*)&Ks[kh*64 + nt*16 + l15][32 + quad*8];
      #pragma unroll
      for (int mt = 0; mt < 2; ++mt){
        f32x4 c = (f32x4){0.f,0.f,0.f,0.f};
        c = mfma16(aq[mt][0], bk0, c);
        c = mfma16(aq[mt][1], bk1, c);
        sf[mt][nt] = c;
      }
    }
    __syncthreads();                 // B2: all Ks reads done -> Ps overlay safe

    // ---- p = exp2(s*ESCALE)*wgt ; write Ps (overlays Ks) ----
    #pragma unroll
    for (int mt = 0; mt < 2; ++mt)
      #pragma unroll
      for (int nt = 0; nt < 4; ++nt)
        #pragma unroll
        for (int r = 0; r < 4; ++r){
          float p = exp2f(sf[mt][nt][r]*ESCALE) * wv[mt][nt][r];
          lsum[mt][r] += p;
          Ps[qh*32 + mt*16 + quad*4 + r][kh*64 + nt*16 + l15] = (bf16)p;
        }
    __syncthreads();                 // B3: Ps complete (cross-wave)

    // ---- PV: wave computes 32q x 32d over full k=128 ----
    #pragma unroll
    for (int kk = 0; kk < 4; ++kk){
      bf16x8 ap[2];
      #pragma unroll
      for (int mt = 0; mt < 2; ++mt)
        ap[mt] = *(const bf16x8*)&Ps[qh*32 + mt*16 + l15][kk*32 + quad*8];
      #pragma unroll
      for (int nt = 0; nt < 2; ++nt){
        bf16x8 bv = *(const bf16x8*)&Vs[kh*32 + nt*16 + l15][kk*32 + quad*8];
        #pragma unroll
        for (int mt = 0; mt < 2; ++mt)
          acc[mt][nt] = mfma16(ap[mt], bv, acc[mt][nt]);
      }
    }
    __syncthreads();                 // B4: PV reads done -> Ks/Vs free for next tile
  }

  // ---- lsum exchange: reduce over l15, publish per (kh, q) ----
  #pragma unroll
  for (int mt = 0; mt < 2; ++mt)
    #pragma unroll
    for (int r = 0; r < 4; ++r){
      float v = lsum[mt][r];
      v += __shfl_xor(v, 1); v += __shfl_xor(v, 2);
      v += __shfl_xor(v, 4); v += __shfl_xor(v, 8);
      if (l15 == 0) lsum_s[kh*64 + qh*32 + mt*16 + quad*4 + r] = v;
    }
  __syncthreads();

  // ---- epilogue: normalize, store (b,s,h,d) bf16 ----
  #pragma unroll
  for (int mt = 0; mt < 2; ++mt){
    #pragma unroll
    for (int r = 0; r < 4; ++r){
      int ql = qh*32 + mt*16 + quad*4 + r;
      float inv = 1.f / (lsum_s[ql] + lsum_s[64 + ql]);
      #pragma unroll
      for (int nt = 0; nt < 2; ++nt){
        int d = kh*32 + nt*16 + l15;
        Out[(size_t)(b*SEQ + q0 + ql)*EMBED + h*HD + d] = (bf16)(acc[mt][nt][r]*inv);
      }
    }
  }
}

// ---------------- launch ----------------
extern "C" void kernel_launch(void* const* d_in, const int* in_sizes, int n_in,
                              void* d_out, int out_size, void* d_ws, size_t ws_size,
                              hipStream_t stream)
{
  (void)in_sizes; (void)n_in; (void)out_size;
  const float* Q  = (const float*)d_in[0];
  const float* K  = (const float*)d_in[1];
  const float* V  = (const float*)d_in[2];
  const int*   ID = (const int*)d_in[3];
  const float* Wq = (const float*)d_in[4];
  const float* Wk = (const float*)d_in[5];
  const float* Wv = (const float*)d_in[6];
  const float* Wo = (const float*)d_in[7];
  const float* RE = (const float*)d_in[8];
  float* out = (float*)d_out;

  const size_t MB = (size_t)1 << 20;
  if (ws_size < 36*MB) return;
  char* ws = (char*)d_ws;
  bf16* Qp  = (bf16*)(ws + 0*MB);
  bf16* Kp  = (bf16*)(ws + 4*MB);
  bf16* Vtw = (bf16*)(ws + 8*MB);     // (b,h,d,s) written by proj z==2
  bf16* AO  = (bf16*)(ws + 12*MB);
  bf16* Wop = (bf16*)(ws + 16*MB);    // 512 KB, written inside k_attn

  k_gemm_proj <<<dim3(4,32,3), 256, 0, stream>>>(Q, K, V, Wq, Wk, Wv, Qp, Kp, Vtw);
  k_attn      <<<dim3(32,8,2), 256, 0, stream>>>(Qp, Kp, Vtw, RE, Wo, ID, AO, Wop);
  k_gemm_out  <<<dim3(8,64),   256, 0, stream>>>(AO, Wop, out);
}

// Round 8
// 226.256 us; speedup vs baseline: 1.7188x; 1.7188x over previous
//
#include <hip/hip_runtime.h>
#include <cstdint>
#include <cstddef>

#define SEQ   2048
#define BBAT  2
#define EMBED 512
#define NH    8
#define HD    64
#define NPOS  34

typedef __bf16 bf16;
typedef __bf16 bf16x8 __attribute__((ext_vector_type(8)));
typedef float  f32x4  __attribute__((ext_vector_type(4)));

// scale = log2(e)/8 : energy=(qk+bias)/8, computed in exp2 domain
#define ESCALE 0.1803368801111204f

__device__ __forceinline__ f32x4 mfma16(bf16x8 a, bf16x8 b, f32x4 c){
  return __builtin_amdgcn_mfma_f32_16x16x32_bf16(a, b, c, 0, 0, 0);
}

// ---------------- projections: 128x128 tile, f32 inputs converted in staging ----------------
// B rows permuted during staging (free): W'[n'][k] = W[(n'&63)*8 + (n'>>6)][k].
// z==2 (V) stores transposed (b,h,d,s) via LDS. Register double-buffer on A and B.
__global__ __launch_bounds__(256,2) void k_gemm_proj(
    const float* __restrict__ Q, const float* __restrict__ K, const float* __restrict__ V,
    const float* __restrict__ Wq, const float* __restrict__ Wk, const float* __restrict__ Wv,
    bf16* __restrict__ Qp, bf16* __restrict__ Kp, bf16* __restrict__ Vt)
{
  __shared__ __align__(16) bf16 smem[18432];          // 36864 B: As[128][72] + Bs[128][72]
  bf16 (*As)[72] = (bf16(*)[72])smem;
  bf16 (*Bs)[72] = (bf16(*)[72])(smem + 9216);
  const int z = blockIdx.z;
  const float* A = z==0 ? Q : (z==1 ? K : V);
  const float* W = z==0 ? Wq : (z==1 ? Wk : Wv);
  const int t = threadIdx.x;
  const int w = t >> 6, lane = t & 63, l15 = lane & 15, quad = lane >> 4;
  const int wm = (w & 1) * 64, wn = (w >> 1) * 64;
  const int m0 = blockIdx.y * 128, n0 = blockIdx.x * 128;

  f32x4 acc[4][4];
  #pragma unroll
  for (int mt=0;mt<4;++mt)
    #pragma unroll
    for (int nt=0;nt<4;++nt) acc[mt][nt] = (f32x4){0.f,0.f,0.f,0.f};

  // prologue: load kt=0 tiles into regs
  float4 pa[8], pb[8];
  #pragma unroll
  for (int i=0;i<8;++i){
    int fl = t + 256*i, row = fl >> 4, c4 = (fl & 15) << 2;
    pa[i] = *(const float4*)(A + (size_t)(m0 + row)*512 + c4);
    int src = (((n0 + row) & 63) << 3) + ((n0 + row) >> 6);
    pb[i] = *(const float4*)(W + (size_t)src*512 + c4);
  }

  for (int kt = 0; kt < 512; kt += 64){
    // regs -> LDS with f32->bf16 convert
    #pragma unroll
    for (int i=0;i<8;++i){
      int fl = t + 256*i, row = fl >> 4, c4 = (fl & 15) << 2;
      union { bf16 e[4]; ushort4 u; } ca, cb;
      ca.e[0]=(bf16)pa[i].x; ca.e[1]=(bf16)pa[i].y; ca.e[2]=(bf16)pa[i].z; ca.e[3]=(bf16)pa[i].w;
      cb.e[0]=(bf16)pb[i].x; cb.e[1]=(bf16)pb[i].y; cb.e[2]=(bf16)pb[i].z; cb.e[3]=(bf16)pb[i].w;
      *(ushort4*)&As[row][c4] = ca.u;
      *(ushort4*)&Bs[row][c4] = cb.u;
    }
    __syncthreads();
    // prefetch next k-tile (VMEM hidden behind MFMA)
    if (kt < 448){
      #pragma unroll
      for (int i=0;i<8;++i){
        int fl = t + 256*i, row = fl >> 4, c4 = (fl & 15) << 2;
        pa[i] = *(const float4*)(A + (size_t)(m0 + row)*512 + kt + 64 + c4);
        int src = (((n0 + row) & 63) << 3) + ((n0 + row) >> 6);
        pb[i] = *(const float4*)(W + (size_t)src*512 + kt + 64 + c4);
      }
    }
    #pragma unroll
    for (int ks = 0; ks < 2; ++ks){
      bf16x8 am[4], bn[4];
      #pragma unroll
      for (int x=0;x<4;++x) am[x] = *(const bf16x8*)&As[wm + x*16 + l15][ks*32 + quad*8];
      #pragma unroll
      for (int y=0;y<4;++y) bn[y] = *(const bf16x8*)&Bs[wn + y*16 + l15][ks*32 + quad*8];
      #pragma unroll
      for (int mt=0;mt<4;++mt)
        #pragma unroll
        for (int nt=0;nt<4;++nt)
          acc[mt][nt] = mfma16(am[mt], bn[nt], acc[mt][nt]);
    }
    __syncthreads();
  }

  if (z != 2){
    bf16* C = z==0 ? Qp : Kp;
    #pragma unroll
    for (int mt=0;mt<4;++mt)
      #pragma unroll
      for (int r=0;r<4;++r){
        int m = m0 + wm + mt*16 + quad*4 + r;
        #pragma unroll
        for (int nt=0;nt<4;++nt)
          C[(size_t)m*512 + n0 + wn + nt*16 + l15] = (bf16)acc[mt][nt][r];
      }
  } else {
    // transpose via LDS overlay (As+Bs region): VT[n_local 128][m 128+pad]
    bf16 (*VT)[136] = (bf16(*)[136])smem;             // 34816 B <= 36864
    #pragma unroll
    for (int mt=0;mt<4;++mt)
      #pragma unroll
      for (int r=0;r<4;++r){
        int m = wm + mt*16 + quad*4 + r;
        #pragma unroll
        for (int nt=0;nt<4;++nt)
          VT[wn + nt*16 + l15][m] = (bf16)acc[mt][nt][r];
      }
    __syncthreads();
    const int nl = t >> 1, half = t & 1;
    const int gh = (n0 + nl) >> 6, d = (n0 + nl) & 63;
    const int b = m0 >> 11, s0 = (m0 & 2047) + half*64;
    bf16* dst = Vt + ((size_t)((b*NH + gh)*HD + d))*SEQ + s0;
    #pragma unroll
    for (int j = 0; j < 8; ++j)
      *(uint4*)(dst + j*8) = *(const uint4*)&VT[nl][half*64 + j*8];
  }
}

// ---------------- GEMM 64x64 tile (output proj, f32 out), register double-buffer ----------------
__global__ __launch_bounds__(256,2) void k_gemm_out(
    const bf16* __restrict__ A, const bf16* __restrict__ Bw, float* __restrict__ C)
{
  __shared__ __align__(16) bf16 As[64][72];
  __shared__ __align__(16) bf16 Bs[64][72];
  const int t = threadIdx.x;
  const int w = t >> 6, lane = t & 63, l15 = lane & 15, quad = lane >> 4;
  const int wm = (w & 1) * 32, wn = (w >> 1) * 32;
  const int m0 = blockIdx.y * 64, n0 = blockIdx.x * 64;

  f32x4 acc[2][2];
  #pragma unroll
  for (int mt=0; mt<2; ++mt)
    #pragma unroll
    for (int nt=0; nt<2; ++nt) acc[mt][nt] = (f32x4){0.f,0.f,0.f,0.f};

  uint4 pa[2], pb[2];
  #pragma unroll
  for (int i=0;i<2;++i){
    int lin = t + 256*i, r = lin >> 3, c8 = (lin & 7) << 3;
    pa[i] = *(const uint4*)(A  + (size_t)(m0 + r)*512 + c8);
    pb[i] = *(const uint4*)(Bw + (size_t)(n0 + r)*512 + c8);
  }

  for (int kt = 0; kt < 512; kt += 64){
    #pragma unroll
    for (int i = 0; i < 2; ++i){
      int lin = t + 256*i, r = lin >> 3, c8 = (lin & 7) << 3;
      *(uint4*)&As[r][c8] = pa[i];
      *(uint4*)&Bs[r][c8] = pb[i];
    }
    __syncthreads();
    if (kt < 448){
      #pragma unroll
      for (int i = 0; i < 2; ++i){
        int lin = t + 256*i, r = lin >> 3, c8 = (lin & 7) << 3;
        pa[i] = *(const uint4*)(A  + (size_t)(m0 + r)*512 + kt + 64 + c8);
        pb[i] = *(const uint4*)(Bw + (size_t)(n0 + r)*512 + kt + 64 + c8);
      }
    }
    #pragma unroll
    for (int ks = 0; ks < 2; ++ks){
      bf16x8 am[2], bn[2];
      #pragma unroll
      for (int x=0;x<2;++x) am[x] = *(const bf16x8*)&As[wm + x*16 + l15][ks*32 + quad*8];
      #pragma unroll
      for (int y=0;y<2;++y) bn[y] = *(const bf16x8*)&Bs[wn + y*16 + l15][ks*32 + quad*8];
      #pragma unroll
      for (int mt=0;mt<2;++mt)
        #pragma unroll
        for (int nt=0;nt<2;++nt)
          acc[mt][nt] = mfma16(am[mt], bn[nt], acc[mt][nt]);
    }
    __syncthreads();
  }
  #pragma unroll
  for (int mt=0;mt<2;++mt)
    #pragma unroll
    for (int r=0;r<4;++r){
      int m = m0 + wm + mt*16 + quad*4 + r;
      #pragma unroll
      for (int nt=0;nt<2;++nt)
        C[(size_t)m*512 + n0 + wn + nt*16 + l15] = acc[mt][nt][r];
    }
}

// ---------------- flash attention: LDS-gather bias, Ps-overlays-Ks, 3 WG/CU ----------------
// grid (32,8,2) x 256 thr. QK square wave sub-tiles (32q x 64k); PV 32q x 32d over k=128.
// lut bf16 [64][36]; bias gathered from LDS banks (TA-serialization was the ~100us wall).
// bounds (256,3): VGPR cap ~168 > ~116 needed -> NO spill. (256,4) spilled: R7, WRITE 304MB.
// Also folds: Wop col-perm table build (for k_gemm_out) + lut B-frags read direct from RE.
__global__ __launch_bounds__(256,3) void k_attn(
    const bf16* __restrict__ Qp, const bf16* __restrict__ Kp,
    const bf16* __restrict__ Vt, const float* __restrict__ RE,
    const float* __restrict__ Wo, const int* __restrict__ ids,
    bf16* __restrict__ Out, bf16* __restrict__ Wop)
{
  // LDS: KP 18432 (Ks[128][72] / Ps[64][136] overlay) + Vs 17408 + lut 4608 + lsum 512 = 40960 B
  __shared__ __align__(16) bf16 KP[9216];
  __shared__ __align__(16) bf16 Vs[64][136];
  __shared__ bf16 lut[64][36];
  __shared__ float lsum_s[128];
  bf16 (*Ks)[72]  = (bf16(*)[72])KP;
  bf16 (*Ps)[136] = (bf16(*)[136])KP;

  const int t = threadIdx.x;
  const int b = blockIdx.z, h = blockIdx.y;
  const int q0 = blockIdx.x * 64;
  const int w = t >> 6, lane = t & 63, l15 = lane & 15, quad = lane >> 4;
  const int qh = w & 1, kh = w >> 1;

  // ---- fold: build one row of Wop (col-permuted Wo, bf16) for k_gemm_out ----
  {
    int n = blockIdx.x + 32*blockIdx.y + 256*blockIdx.z;   // [0,512)
    int kp0 = t*2, kp1 = t*2 + 1;
    int s0i = ((kp0 & 63) << 3) + (kp0 >> 6);
    int s1i = ((kp1 & 63) << 3) + (kp1 >> 6);
    Wop[(size_t)n*512 + kp0] = (bf16)Wo[(size_t)n*512 + s0i];
    Wop[(size_t)n*512 + kp1] = (bf16)Wo[(size_t)n*512 + s1i];
  }

  const size_t idb = (size_t)b*SEQ*SEQ;

  // ---- prefetch tile-0 ids (latency hidden under LUT build) ----
  int nid[2][4][4];
  #pragma unroll
  for (int mt=0; mt<2; ++mt)
    #pragma unroll
    for (int nt=0; nt<4; ++nt)
      #pragma unroll
      for (int r=0; r<4; ++r)
        nid[mt][nt][r] = ids[idb + (size_t)(q0 + qh*32 + mt*16 + quad*4 + r)*SEQ
                             + kh*64 + nt*16 + l15];

  // ---- build LUT via MFMA, B-frags direct from RE (strided f32, L2/L1-resident) ----
  {
    const bf16* qbrow = Qp + (size_t)(b*SEQ + q0 + w*16 + l15)*EMBED + h*HD;
    bf16x8 ab0 = *(const bf16x8*)(qbrow + quad*8);
    bf16x8 ab1 = *(const bf16x8*)(qbrow + 32 + quad*8);
    #pragma unroll
    for (int nt = 0; nt < 3; ++nt){
      int p = nt*16 + l15;
      bf16x8 r0, r1;
      if (p < NPOS){
        #pragma unroll
        for (int j = 0; j < 8; ++j){
          r0[j] = (bf16)RE[(size_t)p*512 + (quad*8 + j)*8 + h];
          r1[j] = (bf16)RE[(size_t)p*512 + (32 + quad*8 + j)*8 + h];
        }
      } else {
        #pragma unroll
        for (int j = 0; j < 8; ++j){ r0[j] = (bf16)0.f; r1[j] = (bf16)0.f; }
      }
      f32x4 c = (f32x4){0.f,0.f,0.f,0.f};
      c = mfma16(ab0, r0, c);
      c = mfma16(ab1, r1, c);
      if (p < NPOS){
        #pragma unroll
        for (int r = 0; r < 4; ++r)
          lut[w*16 + quad*4 + r][p] = (p == 0) ? (bf16)0.f : (bf16)exp2f(c[r]*ESCALE);
      }
    }
  }

  // ---- QK A-frags (reg-resident), rows qh*32+mt*16+l15 ----
  bf16x8 aq[2][2];
  #pragma unroll
  for (int mt = 0; mt < 2; ++mt){
    const bf16* qrow = Qp + (size_t)(b*SEQ + q0 + qh*32 + mt*16 + l15)*EMBED + h*HD;
    aq[mt][0] = *(const bf16x8*)(qrow + quad*8);
    aq[mt][1] = *(const bf16x8*)(qrow + 32 + quad*8);
  }

  const bf16* kbase = Kp + (size_t)b*SEQ*EMBED + h*HD;
  const bf16* vbase = Vt + (size_t)(b*NH + h)*HD*SEQ;

  f32x4 acc[2][2];
  #pragma unroll
  for (int mt=0;mt<2;++mt)
    #pragma unroll
    for (int nt=0;nt<2;++nt) acc[mt][nt] = (f32x4){0.f,0.f,0.f,0.f};
  float lsum[2][4] = {{0.f,0.f,0.f,0.f},{0.f,0.f,0.f,0.f}};

  for (int kt = 0; kt < 16; ++kt){
    const int k0 = kt * 128;
    // ---- stage K (128x64) and V^T (64x128) ----
    #pragma unroll
    for (int i = 0; i < 4; ++i){
      int lin = t + 256*i;
      int r = lin >> 3, c8 = (lin & 7) << 3;
      *(uint4*)&Ks[r][c8] = *(const uint4*)(kbase + (size_t)(k0 + r)*EMBED + c8);
    }
    #pragma unroll
    for (int i = 0; i < 4; ++i){
      int lin = t + 256*i;
      int d = lin >> 4, c8 = (lin & 15) << 3;
      *(uint4*)&Vs[d][c8] = *(const uint4*)(vbase + (size_t)d*SEQ + k0 + c8);
    }
    __syncthreads();                 // B1: staging done (tile 0: also LUT/Wop done)

    // ---- bias gathers from LDS LUT (indices already resident) ----
    float wv[2][4][4];
    #pragma unroll
    for (int mt = 0; mt < 2; ++mt)
      #pragma unroll
      for (int nt = 0; nt < 4; ++nt)
        #pragma unroll
        for (int r = 0; r < 4; ++r)
          wv[mt][nt][r] = (float)lut[qh*32 + mt*16 + quad*4 + r][nid[mt][nt][r]];

    // ---- prefetch next tile ids (VMEM flies under MFMA) ----
    if (kt < 15){
      #pragma unroll
      for (int mt = 0; mt < 2; ++mt)
        #pragma unroll
        for (int nt = 0; nt < 4; ++nt)
          #pragma unroll
          for (int r = 0; r < 4; ++r)
            nid[mt][nt][r] = ids[idb + (size_t)(q0 + qh*32 + mt*16 + quad*4 + r)*SEQ
                                 + (k0 + 128) + kh*64 + nt*16 + l15];
    }

    // ---- QK: wave computes 32q x 64k ----
    f32x4 sf[2][4];
    #pragma unroll
    for (int nt = 0; nt < 4; ++nt){
      bf16x8 bk0 = *(const bf16x8*)&Ks[kh*64 + nt*16 + l15][quad*8];
      bf16x8 bk1 = *(const bf16x8*)&Ks[kh*64 + nt*16 + l15][32 + quad*8];
      #pragma unroll
      for (int mt = 0; mt < 2; ++mt){
        f32x4 c = (f32x4){0.f,0.f,0.f,0.f};
        c = mfma16(aq[mt][0], bk0, c);
        c = mfma16(aq[mt][1], bk1, c);
        sf[mt][nt] = c;
      }
    }
    __syncthreads();                 // B2: all Ks reads done -> Ps overlay safe

    // ---- p = exp2(s*ESCALE)*wgt ; write Ps (overlays Ks) ----
    #pragma unroll
    for (int mt = 0; mt < 2; ++mt)
      #pragma unroll
      for (int nt = 0; nt < 4; ++nt)
        #pragma unroll
        for (int r = 0; r < 4; ++r){
          float p = exp2f(sf[mt][nt][r]*ESCALE) * wv[mt][nt][r];
          lsum[mt][r] += p;
          Ps[qh*32 + mt*16 + quad*4 + r][kh*64 + nt*16 + l15] = (bf16)p;
        }
    __syncthreads();                 // B3: Ps complete (cross-wave)

    // ---- PV: wave computes 32q x 32d over full k=128 ----
    #pragma unroll
    for (int kk = 0; kk < 4; ++kk){
      bf16x8 ap[2];
      #pragma unroll
      for (int mt = 0; mt < 2; ++mt)
        ap[mt] = *(const bf16x8*)&Ps[qh*32 + mt*16 + l15][kk*32 + quad*8];
      #pragma unroll
      for (int nt = 0; nt < 2; ++nt){
        bf16x8 bv = *(const bf16x8*)&Vs[kh*32 + nt*16 + l15][kk*32 + quad*8];
        #pragma unroll
        for (int mt = 0; mt < 2; ++mt)
          acc[mt][nt] = mfma16(ap[mt], bv, acc[mt][nt]);
      }
    }
    __syncthreads();                 // B4: PV reads done -> Ks/Vs free for next tile
  }

  // ---- lsum exchange: reduce over l15, publish per (kh, q) ----
  #pragma unroll
  for (int mt = 0; mt < 2; ++mt)
    #pragma unroll
    for (int r = 0; r < 4; ++r){
      float v = lsum[mt][r];
      v += __shfl_xor(v, 1); v += __shfl_xor(v, 2);
      v += __shfl_xor(v, 4); v += __shfl_xor(v, 8);
      if (l15 == 0) lsum_s[kh*64 + qh*32 + mt*16 + quad*4 + r] = v;
    }
  __syncthreads();

  // ---- epilogue: normalize, store (b,s,h,d) bf16 ----
  #pragma unroll
  for (int mt = 0; mt < 2; ++mt){
    #pragma unroll
    for (int r = 0; r < 4; ++r){
      int ql = qh*32 + mt*16 + quad*4 + r;
      float inv = 1.f / (lsum_s[ql] + lsum_s[64 + ql]);
      #pragma unroll
      for (int nt = 0; nt < 2; ++nt){
        int d = kh*32 + nt*16 + l15;
        Out[(size_t)(b*SEQ + q0 + ql)*EMBED + h*HD + d] = (bf16)(acc[mt][nt][r]*inv);
      }
    }
  }
}

// ---------------- launch ----------------
extern "C" void kernel_launch(void* const* d_in, const int* in_sizes, int n_in,
                              void* d_out, int out_size, void* d_ws, size_t ws_size,
                              hipStream_t stream)
{
  (void)in_sizes; (void)n_in; (void)out_size;
  const float* Q  = (const float*)d_in[0];
  const float* K  = (const float*)d_in[1];
  const float* V  = (const float*)d_in[2];
  const int*   ID = (const int*)d_in[3];
  const float* Wq = (const float*)d_in[4];
  const float* Wk = (const float*)d_in[5];
  const float* Wv = (const float*)d_in[6];
  const float* Wo = (const float*)d_in[7];
  const float* RE = (const float*)d_in[8];
  float* out = (float*)d_out;

  const size_t MB = (size_t)1 << 20;
  if (ws_size < 36*MB) return;
  char* ws = (char*)d_ws;
  bf16* Qp  = (bf16*)(ws + 0*MB);
  bf16* Kp  = (bf16*)(ws + 4*MB);
  bf16* Vtw = (bf16*)(ws + 8*MB);     // (b,h,d,s) written by proj z==2
  bf16* AO  = (bf16*)(ws + 12*MB);
  bf16* Wop = (bf16*)(ws + 16*MB);    // 512 KB, written inside k_attn

  k_gemm_proj <<<dim3(4,32,3), 256, 0, stream>>>(Q, K, V, Wq, Wk, Wv, Qp, Kp, Vtw);
  k_attn      <<<dim3(32,8,2), 256, 0, stream>>>(Qp, Kp, Vtw, RE, Wo, ID, AO, Wop);
  k_gemm_out  <<<dim3(8,64),   256, 0, stream>>>(AO, Wop, out);
}

// Round 9
// 217.027 us; speedup vs baseline: 1.7919x; 1.0425x over previous
//
#include <hip/hip_runtime.h>
#include <cstdint>
#include <cstddef>

#define SEQ   2048
#define BBAT  2
#define EMBED 512
#define NH    8
#define HD    64
#define NPOS  34

typedef __bf16 bf16;
typedef __bf16 bf16x8 __attribute__((ext_vector_type(8)));
typedef float  f32x4  __attribute__((ext_vector_type(4)));

// scale = log2(e)/8 : energy=(qk+bias)/8, computed in exp2 domain
#define ESCALE 0.1803368801111204f

__device__ __forceinline__ f32x4 mfma16(bf16x8 a, bf16x8 b, f32x4 c){
  return __builtin_amdgcn_mfma_f32_16x16x32_bf16(a, b, c, 0, 0, 0);
}

// ---------------- projections: 128x128 tile, f32 inputs converted in staging ----------------
// B rows permuted during staging (free): W'[n'][k] = W[(n'&63)*8 + (n'>>6)][k].
// z==2 (V) stores transposed (b,h,d,s) via LDS. Register double-buffer on A and B.
__global__ __launch_bounds__(256,2) void k_gemm_proj(
    const float* __restrict__ Q, const float* __restrict__ K, const float* __restrict__ V,
    const float* __restrict__ Wq, const float* __restrict__ Wk, const float* __restrict__ Wv,
    bf16* __restrict__ Qp, bf16* __restrict__ Kp, bf16* __restrict__ Vt)
{
  __shared__ __align__(16) bf16 smem[18432];          // 36864 B: As[128][72] + Bs[128][72]
  bf16 (*As)[72] = (bf16(*)[72])smem;
  bf16 (*Bs)[72] = (bf16(*)[72])(smem + 9216);
  const int z = blockIdx.z;
  const float* A = z==0 ? Q : (z==1 ? K : V);
  const float* W = z==0 ? Wq : (z==1 ? Wk : Wv);
  const int t = threadIdx.x;
  const int w = t >> 6, lane = t & 63, l15 = lane & 15, quad = lane >> 4;
  const int wm = (w & 1) * 64, wn = (w >> 1) * 64;
  const int m0 = blockIdx.y * 128, n0 = blockIdx.x * 128;

  f32x4 acc[4][4];
  #pragma unroll
  for (int mt=0;mt<4;++mt)
    #pragma unroll
    for (int nt=0;nt<4;++nt) acc[mt][nt] = (f32x4){0.f,0.f,0.f,0.f};

  // prologue: load kt=0 tiles into regs
  float4 pa[8], pb[8];
  #pragma unroll
  for (int i=0;i<8;++i){
    int fl = t + 256*i, row = fl >> 4, c4 = (fl & 15) << 2;
    pa[i] = *(const float4*)(A + (size_t)(m0 + row)*512 + c4);
    int src = (((n0 + row) & 63) << 3) + ((n0 + row) >> 6);
    pb[i] = *(const float4*)(W + (size_t)src*512 + c4);
  }

  for (int kt = 0; kt < 512; kt += 64){
    // regs -> LDS with f32->bf16 convert
    #pragma unroll
    for (int i=0;i<8;++i){
      int fl = t + 256*i, row = fl >> 4, c4 = (fl & 15) << 2;
      union { bf16 e[4]; ushort4 u; } ca, cb;
      ca.e[0]=(bf16)pa[i].x; ca.e[1]=(bf16)pa[i].y; ca.e[2]=(bf16)pa[i].z; ca.e[3]=(bf16)pa[i].w;
      cb.e[0]=(bf16)pb[i].x; cb.e[1]=(bf16)pb[i].y; cb.e[2]=(bf16)pb[i].z; cb.e[3]=(bf16)pb[i].w;
      *(ushort4*)&As[row][c4] = ca.u;
      *(ushort4*)&Bs[row][c4] = cb.u;
    }
    __syncthreads();
    // prefetch next k-tile (VMEM hidden behind MFMA)
    if (kt < 448){
      #pragma unroll
      for (int i=0;i<8;++i){
        int fl = t + 256*i, row = fl >> 4, c4 = (fl & 15) << 2;
        pa[i] = *(const float4*)(A + (size_t)(m0 + row)*512 + kt + 64 + c4);
        int src = (((n0 + row) & 63) << 3) + ((n0 + row) >> 6);
        pb[i] = *(const float4*)(W + (size_t)src*512 + kt + 64 + c4);
      }
    }
    #pragma unroll
    for (int ks = 0; ks < 2; ++ks){
      bf16x8 am[4], bn[4];
      #pragma unroll
      for (int x=0;x<4;++x) am[x] = *(const bf16x8*)&As[wm + x*16 + l15][ks*32 + quad*8];
      #pragma unroll
      for (int y=0;y<4;++y) bn[y] = *(const bf16x8*)&Bs[wn + y*16 + l15][ks*32 + quad*8];
      #pragma unroll
      for (int mt=0;mt<4;++mt)
        #pragma unroll
        for (int nt=0;nt<4;++nt)
          acc[mt][nt] = mfma16(am[mt], bn[nt], acc[mt][nt]);
    }
    __syncthreads();
  }

  if (z != 2){
    bf16* C = z==0 ? Qp : Kp;
    #pragma unroll
    for (int mt=0;mt<4;++mt)
      #pragma unroll
      for (int r=0;r<4;++r){
        int m = m0 + wm + mt*16 + quad*4 + r;
        #pragma unroll
        for (int nt=0;nt<4;++nt)
          C[(size_t)m*512 + n0 + wn + nt*16 + l15] = (bf16)acc[mt][nt][r];
      }
  } else {
    // transpose via LDS overlay (As+Bs region): VT[n_local 128][m 128+pad]
    bf16 (*VT)[136] = (bf16(*)[136])smem;             // 34816 B <= 36864
    #pragma unroll
    for (int mt=0;mt<4;++mt)
      #pragma unroll
      for (int r=0;r<4;++r){
        int m = wm + mt*16 + quad*4 + r;
        #pragma unroll
        for (int nt=0;nt<4;++nt)
          VT[wn + nt*16 + l15][m] = (bf16)acc[mt][nt][r];
      }
    __syncthreads();
    const int nl = t >> 1, half = t & 1;
    const int gh = (n0 + nl) >> 6, d = (n0 + nl) & 63;
    const int b = m0 >> 11, s0 = (m0 & 2047) + half*64;
    bf16* dst = Vt + ((size_t)((b*NH + gh)*HD + d))*SEQ + s0;
    #pragma unroll
    for (int j = 0; j < 8; ++j)
      *(uint4*)(dst + j*8) = *(const uint4*)&VT[nl][half*64 + j*8];
  }
}

// ---------------- GEMM 64x64 tile (output proj, f32 out), register double-buffer ----------------
__global__ __launch_bounds__(256,2) void k_gemm_out(
    const bf16* __restrict__ A, const bf16* __restrict__ Bw, float* __restrict__ C)
{
  __shared__ __align__(16) bf16 As[64][72];
  __shared__ __align__(16) bf16 Bs[64][72];
  const int t = threadIdx.x;
  const int w = t >> 6, lane = t & 63, l15 = lane & 15, quad = lane >> 4;
  const int wm = (w & 1) * 32, wn = (w >> 1) * 32;
  const int m0 = blockIdx.y * 64, n0 = blockIdx.x * 64;

  f32x4 acc[2][2];
  #pragma unroll
  for (int mt=0; mt<2; ++mt)
    #pragma unroll
    for (int nt=0; nt<2; ++nt) acc[mt][nt] = (f32x4){0.f,0.f,0.f,0.f};

  uint4 pa[2], pb[2];
  #pragma unroll
  for (int i=0;i<2;++i){
    int lin = t + 256*i, r = lin >> 3, c8 = (lin & 7) << 3;
    pa[i] = *(const uint4*)(A  + (size_t)(m0 + r)*512 + c8);
    pb[i] = *(const uint4*)(Bw + (size_t)(n0 + r)*512 + c8);
  }

  for (int kt = 0; kt < 512; kt += 64){
    #pragma unroll
    for (int i = 0; i < 2; ++i){
      int lin = t + 256*i, r = lin >> 3, c8 = (lin & 7) << 3;
      *(uint4*)&As[r][c8] = pa[i];
      *(uint4*)&Bs[r][c8] = pb[i];
    }
    __syncthreads();
    if (kt < 448){
      #pragma unroll
      for (int i = 0; i < 2; ++i){
        int lin = t + 256*i, r = lin >> 3, c8 = (lin & 7) << 3;
        pa[i] = *(const uint4*)(A  + (size_t)(m0 + r)*512 + kt + 64 + c8);
        pb[i] = *(const uint4*)(Bw + (size_t)(n0 + r)*512 + kt + 64 + c8);
      }
    }
    #pragma unroll
    for (int ks = 0; ks < 2; ++ks){
      bf16x8 am[2], bn[2];
      #pragma unroll
      for (int x=0;x<2;++x) am[x] = *(const bf16x8*)&As[wm + x*16 + l15][ks*32 + quad*8];
      #pragma unroll
      for (int y=0;y<2;++y) bn[y] = *(const bf16x8*)&Bs[wn + y*16 + l15][ks*32 + quad*8];
      #pragma unroll
      for (int mt=0;mt<2;++mt)
        #pragma unroll
        for (int nt=0;nt<2;++nt)
          acc[mt][nt] = mfma16(am[mt], bn[nt], acc[mt][nt]);
    }
    __syncthreads();
  }
  #pragma unroll
  for (int mt=0;mt<2;++mt)
    #pragma unroll
    for (int r=0;r<4;++r){
      int m = m0 + wm + mt*16 + quad*4 + r;
      #pragma unroll
      for (int nt=0;nt<2;++nt)
        C[(size_t)m*512 + n0 + wn + nt*16 + l15] = acc[mt][nt][r];
    }
}

// ---------------- flash attention: 32-q tiles, 1024 WGs (4 WG/CU), LDS-gather bias ----------------
// grid (64,8,2) x 256 thr. QK waves: (qh=w&1 -> 16q, kh=w>>1 -> 64k); PV: 16q x 32d over k=128.
// bounds (256,2): the ONLY non-spilling config for this body (R7/R8: (256,4)->64 VGPR
// catastrophic spill, (256,3)->84 mild spill). Occupancy comes from grid size instead.
// Also folds: Wop col-perm table build (for k_gemm_out) + lut B-frags read direct from RE.
__global__ __launch_bounds__(256,2) void k_attn(
    const bf16* __restrict__ Qp, const bf16* __restrict__ Kp,
    const bf16* __restrict__ Vt, const float* __restrict__ RE,
    const float* __restrict__ Wo, const int* __restrict__ ids,
    bf16* __restrict__ Out, bf16* __restrict__ Wop)
{
  // LDS: KP 18432 (Ks[128][72] / Ps[32][136] overlay) + Vs 17408 + lut 2304 + lsum 256 = 38400 B
  // -> 4 WG/CU (153600 <= 163840)
  __shared__ __align__(16) bf16 KP[9216];
  __shared__ __align__(16) bf16 Vs[64][136];
  __shared__ bf16 lut[32][36];
  __shared__ float lsum_s[2][32];
  bf16 (*Ks)[72]  = (bf16(*)[72])KP;
  bf16 (*Ps)[136] = (bf16(*)[136])KP;

  const int t = threadIdx.x;
  const int b = blockIdx.z, h = blockIdx.y;
  const int q0 = blockIdx.x * 32;
  const int w = t >> 6, lane = t & 63, l15 = lane & 15, quad = lane >> 4;
  const int qh = w & 1, kh = w >> 1;

  // ---- fold: build one row of Wop (col-permuted Wo, bf16) for k_gemm_out ----
  {
    int n = blockIdx.x + 64*blockIdx.y + 512*blockIdx.z;   // [0,1024)
    if (n < 512){
      int kp0 = t*2, kp1 = t*2 + 1;
      int s0i = ((kp0 & 63) << 3) + (kp0 >> 6);
      int s1i = ((kp1 & 63) << 3) + (kp1 >> 6);
      Wop[(size_t)n*512 + kp0] = (bf16)Wo[(size_t)n*512 + s0i];
      Wop[(size_t)n*512 + kp1] = (bf16)Wo[(size_t)n*512 + s1i];
    }
  }

  const size_t idb = (size_t)b*SEQ*SEQ;

  // ---- prefetch tile-0 ids (latency hidden under LUT build) ----
  int nid[4][4];
  #pragma unroll
  for (int nt=0; nt<4; ++nt)
    #pragma unroll
    for (int r=0; r<4; ++r)
      nid[nt][r] = ids[idb + (size_t)(q0 + qh*16 + quad*4 + r)*SEQ
                       + kh*64 + nt*16 + l15];

  // ---- build LUT via MFMA (waves 0-1 cover the 32 q rows), B-frags direct from RE ----
  if (w < 2){
    const bf16* qbrow = Qp + (size_t)(b*SEQ + q0 + w*16 + l15)*EMBED + h*HD;
    bf16x8 ab0 = *(const bf16x8*)(qbrow + quad*8);
    bf16x8 ab1 = *(const bf16x8*)(qbrow + 32 + quad*8);
    #pragma unroll
    for (int nt = 0; nt < 3; ++nt){
      int p = nt*16 + l15;
      bf16x8 r0, r1;
      if (p < NPOS){
        #pragma unroll
        for (int j = 0; j < 8; ++j){
          r0[j] = (bf16)RE[(size_t)p*512 + (quad*8 + j)*8 + h];
          r1[j] = (bf16)RE[(size_t)p*512 + (32 + quad*8 + j)*8 + h];
        }
      } else {
        #pragma unroll
        for (int j = 0; j < 8; ++j){ r0[j] = (bf16)0.f; r1[j] = (bf16)0.f; }
      }
      f32x4 c = (f32x4){0.f,0.f,0.f,0.f};
      c = mfma16(ab0, r0, c);
      c = mfma16(ab1, r1, c);
      if (p < NPOS){
        #pragma unroll
        for (int r = 0; r < 4; ++r)
          lut[w*16 + quad*4 + r][p] = (p == 0) ? (bf16)0.f : (bf16)exp2f(c[r]*ESCALE);
      }
    }
  }

  // ---- QK A-frags (reg-resident), rows qh*16+l15 ----
  bf16x8 aq0, aq1;
  {
    const bf16* qrow = Qp + (size_t)(b*SEQ + q0 + qh*16 + l15)*EMBED + h*HD;
    aq0 = *(const bf16x8*)(qrow + quad*8);
    aq1 = *(const bf16x8*)(qrow + 32 + quad*8);
  }

  const bf16* kbase = Kp + (size_t)b*SEQ*EMBED + h*HD;
  const bf16* vbase = Vt + (size_t)(b*NH + h)*HD*SEQ;

  f32x4 acc[2];
  acc[0] = (f32x4){0.f,0.f,0.f,0.f};
  acc[1] = (f32x4){0.f,0.f,0.f,0.f};
  float lsum[4] = {0.f,0.f,0.f,0.f};

  for (int kt = 0; kt < 16; ++kt){
    const int k0 = kt * 128;
    // ---- stage K (128x64) and V^T (64x128) ----
    #pragma unroll
    for (int i = 0; i < 4; ++i){
      int lin = t + 256*i;
      int r = lin >> 3, c8 = (lin & 7) << 3;
      *(uint4*)&Ks[r][c8] = *(const uint4*)(kbase + (size_t)(k0 + r)*EMBED + c8);
    }
    #pragma unroll
    for (int i = 0; i < 4; ++i){
      int lin = t + 256*i;
      int d = lin >> 4, c8 = (lin & 15) << 3;
      *(uint4*)&Vs[d][c8] = *(const uint4*)(vbase + (size_t)d*SEQ + k0 + c8);
    }
    __syncthreads();                 // B1: staging done (tile 0: also LUT/Wop done)

    // ---- bias gathers from LDS LUT (indices already resident) ----
    float wv[4][4];
    #pragma unroll
    for (int nt = 0; nt < 4; ++nt)
      #pragma unroll
      for (int r = 0; r < 4; ++r)
        wv[nt][r] = (float)lut[qh*16 + quad*4 + r][nid[nt][r]];

    // ---- prefetch next tile ids (VMEM flies under MFMA) ----
    if (kt < 15){
      #pragma unroll
      for (int nt = 0; nt < 4; ++nt)
        #pragma unroll
        for (int r = 0; r < 4; ++r)
          nid[nt][r] = ids[idb + (size_t)(q0 + qh*16 + quad*4 + r)*SEQ
                           + (k0 + 128) + kh*64 + nt*16 + l15];
    }

    // ---- QK: wave computes 16q x 64k ----
    f32x4 sf[4];
    #pragma unroll
    for (int nt = 0; nt < 4; ++nt){
      bf16x8 bk0 = *(const bf16x8*)&Ks[kh*64 + nt*16 + l15][quad*8];
      bf16x8 bk1 = *(const bf16x8*)&Ks[kh*64 + nt*16 + l15][32 + quad*8];
      f32x4 c = (f32x4){0.f,0.f,0.f,0.f};
      c = mfma16(aq0, bk0, c);
      c = mfma16(aq1, bk1, c);
      sf[nt] = c;
    }
    __syncthreads();                 // B2: all Ks reads done -> Ps overlay safe

    // ---- p = exp2(s*ESCALE)*wgt ; write Ps (overlays Ks) ----
    #pragma unroll
    for (int nt = 0; nt < 4; ++nt)
      #pragma unroll
      for (int r = 0; r < 4; ++r){
        float p = exp2f(sf[nt][r]*ESCALE) * wv[nt][r];
        lsum[r] += p;
        Ps[qh*16 + quad*4 + r][kh*64 + nt*16 + l15] = (bf16)p;
      }
    __syncthreads();                 // B3: Ps complete (cross-wave)

    // ---- PV: wave computes 16q x 32d over full k=128 ----
    #pragma unroll
    for (int kk = 0; kk < 4; ++kk){
      bf16x8 ap = *(const bf16x8*)&Ps[qh*16 + l15][kk*32 + quad*8];
      #pragma unroll
      for (int nt = 0; nt < 2; ++nt){
        bf16x8 bv = *(const bf16x8*)&Vs[kh*32 + nt*16 + l15][kk*32 + quad*8];
        acc[nt] = mfma16(ap, bv, acc[nt]);
      }
    }
    __syncthreads();                 // B4: PV reads done -> Ks/Vs free for next tile
  }

  // ---- lsum exchange: reduce over l15, publish per (kh, q) ----
  #pragma unroll
  for (int r = 0; r < 4; ++r){
    float v = lsum[r];
    v += __shfl_xor(v, 1); v += __shfl_xor(v, 2);
    v += __shfl_xor(v, 4); v += __shfl_xor(v, 8);
    if (l15 == 0) lsum_s[kh][qh*16 + quad*4 + r] = v;
  }
  __syncthreads();

  // ---- epilogue: normalize, store (b,s,h,d) bf16 ----
  #pragma unroll
  for (int r = 0; r < 4; ++r){
    int ql = qh*16 + quad*4 + r;
    float inv = 1.f / (lsum_s[0][ql] + lsum_s[1][ql]);
    #pragma unroll
    for (int nt = 0; nt < 2; ++nt){
      int d = kh*32 + nt*16 + l15;
      Out[(size_t)(b*SEQ + q0 + ql)*EMBED + h*HD + d] = (bf16)(acc[nt][r]*inv);
    }
  }
}

// ---------------- launch ----------------
extern "C" void kernel_launch(void* const* d_in, const int* in_sizes, int n_in,
                              void* d_out, int out_size, void* d_ws, size_t ws_size,
                              hipStream_t stream)
{
  (void)in_sizes; (void)n_in; (void)out_size;
  const float* Q  = (const float*)d_in[0];
  const float* K  = (const float*)d_in[1];
  const float* V  = (const float*)d_in[2];
  const int*   ID = (const int*)d_in[3];
  const float* Wq = (const float*)d_in[4];
  const float* Wk = (const float*)d_in[5];
  const float* Wv = (const float*)d_in[6];
  const float* Wo = (const float*)d_in[7];
  const float* RE = (const float*)d_in[8];
  float* out = (float*)d_out;

  const size_t MB = (size_t)1 << 20;
  if (ws_size < 36*MB) return;
  char* ws = (char*)d_ws;
  bf16* Qp  = (bf16*)(ws + 0*MB);
  bf16* Kp  = (bf16*)(ws + 4*MB);
  bf16* Vtw = (bf16*)(ws + 8*MB);     // (b,h,d,s) written by proj z==2
  bf16* AO  = (bf16*)(ws + 12*MB);
  bf16* Wop = (bf16*)(ws + 16*MB);    // 512 KB, written inside k_attn

  k_gemm_proj <<<dim3(4,32,3), 256, 0, stream>>>(Q, K, V, Wq, Wk, Wv, Qp, Kp, Vtw);
  k_attn      <<<dim3(64,8,2), 256, 0, stream>>>(Qp, Kp, Vtw, RE, Wo, ID, AO, Wop);
  k_gemm_out  <<<dim3(8,64),   256, 0, stream>>>(AO, Wop, out);
}